// Round 7
// baseline (327.644 us; speedup 1.0000x reference)
//
#include <hip/hip_runtime.h>
#include <hip/hip_bf16.h>
#include <math.h>

// Shapes (fixed by the reference)
#define B_   128
#define W_   512
#define D_   2048
#define H_   16
#define DH_  128

typedef __attribute__((ext_vector_type(4))) float f32x4;
typedef __attribute__((ext_vector_type(8))) short bf16x8;

__device__ inline short f2bf(float f) {
  union { __hip_bfloat16 h; short s; } u;
  u.h = __float2bfloat16(f);
  return u.s;
}
__device__ inline float bf2f(unsigned short u) {
  return __uint_as_float(((unsigned)u) << 16);
}

// raw barrier: drain LDS ops but NOT in-flight global loads (vmcnt).
#define LGKM_BARRIER() do {                                   \
    asm volatile("s_waitcnt lgkmcnt(0)" ::: "memory");        \
    __builtin_amdgcn_sched_barrier(0);                        \
    __builtin_amdgcn_s_barrier();                             \
    __builtin_amdgcn_sched_barrier(0);                        \
  } while (0)

// ---------------------------------------------------------------------------
// bf16 MFMA GEMM, M = 128 always.  C[m,n] = sum_k A[m,k] * B[n,k].
// (unchanged from R3/R6)
// ---------------------------------------------------------------------------
template<bool BBF16>
__global__ __launch_bounds__(256) void gemm_mfma(
    const float* __restrict__ A, int a_rs, long a_hs,
    const float* __restrict__ A2, int a2_k,
    const void* __restrict__ Bv, int b_rs, long b_hs,
    float* __restrict__ C, int c_rs, long c_hs, long c_ks,
    int Kblk)
{
  __shared__ char sm[2][24576];

  const int t  = threadIdx.x;
  const int w  = t >> 6, l = t & 63, lo = l & 15, hi = l >> 4;
  const int wm = w >> 1, wn = w & 1;
  const int n0   = blockIdx.x * 64;
  const int head = blockIdx.y;
  const int ks   = blockIdx.z;
  const int kbeg = ks * Kblk;
  const int nit  = Kblk >> 6;

  const float* Ab;
  {
    const float* base = A;
    int koff = kbeg;
    if (A2 && kbeg >= a2_k) { base = A2; koff = kbeg - a2_k; }
    Ab = base + head * a_hs + koff;
  }
  const float*          Bf = (const float*)Bv          + (BBF16 ? 0 : head * b_hs + (long)n0 * b_rs + kbeg);
  const unsigned short* Bh = (const unsigned short*)Bv + (BBF16 ? head * b_hs + (long)n0 * b_rs + kbeg : 0);

  const int ar = t >> 2;
  const int ak = (t & 3) * 16;

  f32x4 acc[4][2] = {};

  auto load_tiles = [&](int it, float4* ar4, float4* br4) {
    const float* Ait = Ab + it * 64;
#pragma unroll
    for (int p = 0; p < 2; ++p) {
      const float* src = Ait + (long)(p * 64 + ar) * a_rs + ak;
#pragma unroll
      for (int qq = 0; qq < 4; ++qq) ar4[p * 4 + qq] = *(const float4*)(src + qq * 4);
    }
    if (BBF16) {
      const char* src = (const char*)(Bh + (long)ar * b_rs + it * 64 + ak);
      br4[0] = *(const float4*)(src);
      br4[1] = *(const float4*)(src + 16);
    } else {
      const float* src = Bf + (long)ar * b_rs + it * 64 + ak;
#pragma unroll
      for (int qq = 0; qq < 4; ++qq) br4[qq] = *(const float4*)(src + qq * 4);
    }
  };

  auto write_tiles = [&](int buf, const float4* ar4, const float4* br4) {
    char* As = sm[buf];
    char* Bs = sm[buf] + 16384;
#pragma unroll
    for (int p = 0; p < 2; ++p) {
      int m = p * 64 + ar;
      int base = m * 128 + ak * 2;
      int swz = (m & 7) << 4;
#pragma unroll
      for (int h2 = 0; h2 < 2; ++h2) {
        bf16x8 v;
        const float* f = (const float*)(ar4 + p * 4);
#pragma unroll
        for (int j = 0; j < 8; ++j) v[j] = f2bf(f[h2 * 8 + j]);
        *(bf16x8*)(As + ((base + h2 * 16) ^ swz)) = v;
      }
    }
    {
      int n = ar;
      int base = n * 128 + ak * 2;
      int swz = (n & 7) << 4;
      if (BBF16) {
#pragma unroll
        for (int h2 = 0; h2 < 2; ++h2)
          *(bf16x8*)(Bs + ((base + h2 * 16) ^ swz)) = ((const bf16x8*)br4)[h2];
      } else {
#pragma unroll
        for (int h2 = 0; h2 < 2; ++h2) {
          bf16x8 v;
          const float* f = (const float*)br4;
#pragma unroll
          for (int j = 0; j < 8; ++j) v[j] = f2bf(f[h2 * 8 + j]);
          *(bf16x8*)(Bs + ((base + h2 * 16) ^ swz)) = v;
        }
      }
    }
  };

  auto compute = [&](int buf) {
    const char* As = sm[buf];
    const char* Bs = sm[buf] + 16384;
#pragma unroll
    for (int kk = 0; kk < 2; ++kk) {
      bf16x8 af[4], bfr[2];
#pragma unroll
      for (int mi = 0; mi < 4; ++mi) {
        int m = wm * 64 + mi * 16 + lo;
        af[mi] = *(const bf16x8*)(As + ((m * 128 + (kk * 32 + hi * 8) * 2) ^ ((m & 7) << 4)));
      }
#pragma unroll
      for (int ni = 0; ni < 2; ++ni) {
        int n = wn * 32 + ni * 16 + lo;
        bfr[ni] = *(const bf16x8*)(Bs + ((n * 128 + (kk * 32 + hi * 8) * 2) ^ ((n & 7) << 4)));
      }
#pragma unroll
      for (int mi = 0; mi < 4; ++mi)
#pragma unroll
        for (int ni = 0; ni < 2; ++ni)
          acc[mi][ni] = __builtin_amdgcn_mfma_f32_16x16x32_bf16(af[mi], bfr[ni], acc[mi][ni], 0, 0, 0);
    }
  };

  float4 ar4[8], br4[4];
  load_tiles(0, ar4, br4);
  write_tiles(0, ar4, br4);
  __syncthreads();
  for (int it = 0; it < nit; ++it) {
    float4 na[8], nb[4];
    if (it + 1 < nit) load_tiles(it + 1, na, nb);
    compute(it & 1);
    if (it + 1 < nit) write_tiles((it + 1) & 1, na, nb);
    __syncthreads();
  }

  float* Cb = C + c_ks * ks + c_hs * head + n0;
#pragma unroll
  for (int mi = 0; mi < 4; ++mi)
#pragma unroll
    for (int ni = 0; ni < 2; ++ni)
#pragma unroll
      for (int r = 0; r < 4; ++r)
        Cb[(long)(wm * 64 + mi * 16 + hi * 4 + r) * c_rs + (wn * 32 + ni * 16 + lo)] = acc[mi][ni][r];
}

// ---------------------------------------------------------------------------
// WkT[h][e][d] (bf16) = Wk[h*128+d][e].  (unchanged)
// ---------------------------------------------------------------------------
__global__ __launch_bounds__(256) void transpose_wk(
    const float* __restrict__ Wk, unsigned short* __restrict__ WkT)
{
  __shared__ float tile[64][68];
  const int t  = threadIdx.x;
  const int e0 = blockIdx.x * 64;
  const int d0 = blockIdx.y * 64;
  const int h  = blockIdx.z;
  {
    int d = t >> 2, eq = (t & 3) * 16;
    const float* src = Wk + (long)(h * DH_ + d0 + d) * D_ + e0 + eq;
#pragma unroll
    for (int qq = 0; qq < 4; ++qq)
      *(float4*)&tile[d][eq + qq * 4] = *(const float4*)(src + qq * 4);
  }
  __syncthreads();
  {
    int e = t >> 2, dq = (t & 3) * 16;
    unsigned short* dst = WkT + ((long)h * D_ + e0 + e) * DH_ + d0 + dq;
    bf16x8 v0, v1;
#pragma unroll
    for (int j = 0; j < 8; ++j) v0[j] = f2bf(tile[dq + j][e]);
#pragma unroll
    for (int j = 0; j < 8; ++j) v1[j] = f2bf(tile[dq + 8 + j][e]);
    *(bf16x8*)dst = v0;
    *(bf16x8*)(dst + 8) = v1;
  }
}

// ---------------------------------------------------------------------------
__global__ void reduce_add_k(const float* __restrict__ part, int ns, long stride,
                             long n, float* __restrict__ out)
{
  for (long i = (long)blockIdx.x * blockDim.x + threadIdx.x; i < n;
       i += (long)gridDim.x * blockDim.x) {
    float s = 0.f;
    for (int k = 0; k < ns; ++k) s += part[k * stride + i];
    out[i] = s;
  }
}

// ---------------------------------------------------------------------------
// Fused flash attention v4: bf16 KV tiles (8 rows x 2048 e = 32 KB), THREE
// LDS buffers, prefetch distance 2 (loads for t+2 issued at top of t,
// vmcnt-waited at top of t+1 -> a full iteration of slack). All barriers are
// lgkm-only; no vmcnt drain anywhere in the loop.
//   staging: wave w loads half-row (r=w>>1, half=w&1) fp32 -> perm-truncate
//   to bf16 (1 instr/pair) -> 2x ds_write_b128.  LDS element e of row r at
//   byte r*4096 + (e>>9)*1024 + (((e>>3)&63)*16 ^ ((r&7)<<4)) + (e&7)*2.
// ---------------------------------------------------------------------------
__global__ __launch_bounds__(1024, 4) void fused_attn(
    const float* __restrict__ x, const float* __restrict__ buffer,
    const float* __restrict__ qt, unsigned short* __restrict__ part,
    float* __restrict__ ml)
{
  __shared__ unsigned short kvh[3][8 * 2048];   // 3 x 32 KB bf16 tiles
  __shared__ float lacc[16][8][16];             // partials [wave][s][h]
  __shared__ float pbuf[16][8];                 // P fp32 [h][s]
  __shared__ float sbuf[16];                    // per-h rescale factor

  const int b    = blockIdx.x;
  const int half = blockIdx.y;
  const int t    = threadIdx.x;
  const int w    = t >> 6;
  const int ln   = t & 63;
  const int lo   = ln & 15;
  const int hi   = ln >> 4;

  const int sr  = w >> 1;   // staged row 0..7
  const int shf = w & 1;    // staged half (elem offset shf*1024)

  // q~ A-frags for this wave's e-band (scale folded in), bf16 RNE (once)
  bf16x8 afrag[4];
  {
    const float* qrow = qt + ((long)b * H_ + lo) * D_;
    const float sc = 0.088388347648318447f;  // 1/sqrt(128)
#pragma unroll
    for (int kk = 0; kk < 4; ++kk) {
      int e0 = w * 128 + kk * 32 + hi * 8;
#pragma unroll
      for (int j = 0; j < 8; ++j) afrag[kk][j] = f2bf(qrow[e0 + j] * sc);
    }
  }

  float accE[16][2];
#pragma unroll
  for (int h = 0; h < 16; ++h) { accE[h][0] = 0.f; accE[h][1] = 0.f; }
  float m_run = -1e30f, l_run = 0.f;   // valid in waves 0-3

  float4 rg[4];   // staged fp32 (16 floats): c-blocks {e=shf*1024+c*512+ln*8}

  auto stage_load = [&](int tl) {
    int s_glob = half * 256 + tl * 8 + sr;
    const float* row = ((s_glob < W_ - 1)
        ? buffer + (((long)(b * W_ + s_glob + 1)) << 11)
        : x + ((long)b << 11)) + shf * 1024;
#pragma unroll
    for (int c = 0; c < 2; ++c) {
      const float* p = row + c * 512 + ln * 8;
      rg[c * 2]     = *(const float4*)p;
      rg[c * 2 + 1] = *(const float4*)(p + 4);
    }
  };

  // truncation-pack (v_perm per pair) and write with XOR row swizzle
  auto pack_write = [&](int bi) {
    char* dst = (char*)kvh[bi] + sr * 4096 + shf * 2048;
    const unsigned swz = (unsigned)((sr & 7) << 4);
#pragma unroll
    for (int c = 0; c < 2; ++c) {
      unsigned u[4];
      const float* f = (const float*)&rg[c * 2];
#pragma unroll
      for (int j = 0; j < 4; ++j)
        u[j] = __builtin_amdgcn_perm(__float_as_uint(f[2 * j + 1]),
                                     __float_as_uint(f[2 * j]), 0x07060302u);
      *(uint4*)(dst + c * 1024 + (((unsigned)(ln * 16)) ^ swz)) = *(const uint4*)u;
    }
  };

  // prologue: tile0 written, tile1 in regs
  stage_load(0);
  pack_write(0);
  stage_load(1);
  LGKM_BARRIER();

  int cur = 0;   // buffer index of current tile
  for (int tile = 0; tile < 32; ++tile) {
    const int nxt = (cur == 2) ? 0 : cur + 1;

    // write tile t+1 (regs held since last iteration; vmcnt wait auto),
    // then issue loads for tile t+2 into the freed regs.
    if (tile + 1 < 32) pack_write(nxt);
    if (tile + 2 < 32) stage_load(tile + 2);

    const char* kb = (const char*)kvh[cur];

    // ---- logits: per-wave e-band partial via MFMA (bf16 frags direct)
    {
      f32x4 c4 = {0.f, 0.f, 0.f, 0.f};
      const int srow = lo & 7;   // cols 8..15 duplicate rows 0..7
      const char* rowp = kb + srow * 4096;
      const unsigned swz = (unsigned)(srow << 4);
#pragma unroll
      for (int kk = 0; kk < 4; ++kk) {
        int e0 = w * 128 + kk * 32 + hi * 8;
        unsigned byi = (unsigned)((e0 >> 9) * 1024) + ((((unsigned)((e0 >> 3) & 63)) * 16) ^ swz);
        bf16x8 bv = *(const bf16x8*)(rowp + byi);
        c4 = __builtin_amdgcn_mfma_f32_16x16x32_bf16(afrag[kk], bv, c4, 0, 0, 0);
      }
      if (lo < 8) *(f32x4*)&lacc[w][lo][hi * 4] = c4;
    }
    LGKM_BARRIER();                    // B1: partials visible

    // ---- reduce + online softmax: waves 0-3, wave wr owns h = wr*4+hi
    if (w < 4) {
      const int h = w * 4 + hi;
      const int s = lo & 7;
      float v = 0.f;
#pragma unroll
      for (int ww = 0; ww < 16; ++ww) v += lacc[ww][s][h];
      float mt = v;
      mt = fmaxf(mt, __shfl_xor(mt, 1));
      mt = fmaxf(mt, __shfl_xor(mt, 2));
      mt = fmaxf(mt, __shfl_xor(mt, 4));
      float m_new = fmaxf(m_run, mt);
      float scl = __expf(m_run - m_new);
      float p = __expf(v - m_new);
      float ps = p;
      ps += __shfl_xor(ps, 1);
      ps += __shfl_xor(ps, 2);
      ps += __shfl_xor(ps, 4);
      l_run = l_run * scl + ps;
      m_run = m_new;
      if (lo < 8) pbuf[h][s] = p;
      if (lo == 0) sbuf[h] = scl;
    }
    LGKM_BARRIER();                    // B2: pbuf/sbuf ready

    // ---- rescale + PV. lane owns e = 128w + 2*ln (+1); bf16 unpack.
    {
      const int e0 = w * 128 + ln * 2;
      const unsigned base = (unsigned)((e0 >> 9) * 1024 + (((e0 >> 3) & 63) * 16) + (e0 & 7) * 2);
      float ke0[8], ke1[8];
#pragma unroll
      for (int s = 0; s < 8; ++s) {
        unsigned u = *(const unsigned*)(kb + s * 4096 + (base ^ ((unsigned)(s << 4))));
        ke0[s] = __uint_as_float(u << 16);
        ke1[s] = __uint_as_float(u & 0xffff0000u);
      }
#pragma unroll
      for (int h = 0; h < 16; ++h) {
        float scl = sbuf[h];
        float a0 = accE[h][0] * scl, a1 = accE[h][1] * scl;
        float4 pA = *(const float4*)&pbuf[h][0];
        float4 pB = *(const float4*)&pbuf[h][4];
        a0 += pA.x * ke0[0] + pA.y * ke0[1] + pA.z * ke0[2] + pA.w * ke0[3]
            + pB.x * ke0[4] + pB.y * ke0[5] + pB.z * ke0[6] + pB.w * ke0[7];
        a1 += pA.x * ke1[0] + pA.y * ke1[1] + pA.z * ke1[2] + pA.w * ke1[3]
            + pB.x * ke1[4] + pB.y * ke1[5] + pB.z * ke1[6] + pB.w * ke1[7];
        accE[h][0] = a0; accE[h][1] = a1;
      }
    }
    LGKM_BARRIER();                    // B3: tile t+1 writes drained+visible
    cur = nxt;
  }

  // ---- epilogue: unnormalized acc (bf16) + (m,l)
  {
    long base = ((long)half * B_ + b) * H_;
#pragma unroll
    for (int h = 0; h < 16; ++h) {
      long idx = (base + h) * D_ + w * 128 + ln * 2;
      unsigned u0 = (unsigned short)f2bf(accE[h][0]);
      unsigned u1 = (unsigned short)f2bf(accE[h][1]);
      *(unsigned*)(part + idx) = u0 | (u1 << 16);
    }
    if (w < 4 && lo == 0) {
      ml[(base + w * 4 + hi) * 2 + 0] = m_run;
      ml[(base + w * 4 + hi) * 2 + 1] = l_run;
    }
  }
}

// ---------------------------------------------------------------------------
__global__ __launch_bounds__(256) void combine_k(
    const unsigned short* __restrict__ part, const float* __restrict__ ml,
    float* __restrict__ vt)
{
  const int bh = blockIdx.x;
  const float m0 = ml[bh * 2],          l0 = ml[bh * 2 + 1];
  const float m1 = ml[(2048 + bh) * 2], l1 = ml[(2048 + bh) * 2 + 1];
  const float M  = fmaxf(m0, m1);
  const float w0 = __expf(m0 - M), w1 = __expf(m1 - M);
  const float inv = 1.0f / (w0 * l0 + w1 * l1);
  const unsigned short* p0 = part + (long)bh * D_;
  const unsigned short* p1 = part + (long)(2048 + bh) * D_;
  float* out = vt + (long)bh * D_;

  const int e = threadIdx.x * 8;
  ushort4 a1 = *(const ushort4*)(p0 + e);
  ushort4 a2 = *(const ushort4*)(p0 + e + 4);
  ushort4 b1 = *(const ushort4*)(p1 + e);
  ushort4 b2 = *(const ushort4*)(p1 + e + 4);
  float oa[8], ob[8];
  oa[0]=bf2f(a1.x); oa[1]=bf2f(a1.y); oa[2]=bf2f(a1.z); oa[3]=bf2f(a1.w);
  oa[4]=bf2f(a2.x); oa[5]=bf2f(a2.y); oa[6]=bf2f(a2.z); oa[7]=bf2f(a2.w);
  ob[0]=bf2f(b1.x); ob[1]=bf2f(b1.y); ob[2]=bf2f(b1.z); ob[3]=bf2f(b1.w);
  ob[4]=bf2f(b2.x); ob[5]=bf2f(b2.y); ob[6]=bf2f(b2.z); ob[7]=bf2f(b2.w);
#pragma unroll
  for (int j = 0; j < 8; ++j) out[e + j] = (w0 * oa[j] + w1 * ob[j]) * inv;
}

// ---------------------------------------------------------------------------
__global__ __launch_bounds__(256) void gate_final_k(
    const float* __restrict__ part, const float* __restrict__ bg,
    const float* __restrict__ x, const float* __restrict__ out1,
    float* __restrict__ y)
{
  const long i = (long)blockIdx.x * 256 + threadIdx.x;
  float z = bg[i & (D_ - 1)];
#pragma unroll
  for (int k = 0; k < 8; ++k) z += part[(long)k * (B_ * D_) + i];
  const float g = 1.0f / (1.0f + expf(-z));
  y[i] = x[i] + g * out1[i];
}

// ---------------------------------------------------------------------------
extern "C" void kernel_launch(void* const* d_in, const int* in_sizes, int n_in,
                              void* d_out, int out_size, void* d_ws, size_t ws_size,
                              hipStream_t stream)
{
  const float* x      = (const float*)d_in[0];
  const float* buffer = (const float*)d_in[1];
  const float* Wq     = (const float*)d_in[2];
  const float* Wk     = (const float*)d_in[3];
  const float* Wv     = (const float*)d_in[4];
  const float* Wo     = (const float*)d_in[5];
  const float* Wg     = (const float*)d_in[6];
  const float* bg     = (const float*)d_in[7];
  float* y = (float*)d_out;

  // workspace layout (float units)
  float* ws    = (float*)d_ws;
  float* q     = ws;                        // 262144
  float* qt    = ws + 262144;               // 4194304 (vt aliases after fused)
  float* vt    = qt;
  unsigned short* part_a = (unsigned short*)(ws + 4456448); // 8388608 bf16
  float* ml    = ws + 8650752;              // 8192
  float* o0    = ws + 8658944;              // 262144
  float* o1    = ws + 8921088;              // 262144
  float* partg = ws + 9183232;              // 8 * 262144 = 2097152
  unsigned short* wkT = (unsigned short*)(ws + 11280384);   // 16*2048*128 bf16

  const long S = (long)B_ * D_;

  // 0) WkT[h][e][d] bf16
  transpose_wk<<<dim3(32, 2, 16), 256, 0, stream>>>(Wk, wkT);

  // 1) q = x @ Wq.T   (K=2048, ksplit 8)
  gemm_mfma<false><<<dim3(32, 1, 8), 256, 0, stream>>>(
      x, D_, 0, nullptr, 1 << 30, Wq, D_, 0, partg, D_, 0, S, 256);
  reduce_add_k<<<512, 256, 0, stream>>>(partg, 8, S, S, q);

  // 2) qt[b,h,e] = sum_d q[b,h*128+d] * WkT[h][e][d]   (K=128, per-head)
  gemm_mfma<true><<<dim3(32, 16, 1), 256, 0, stream>>>(
      q, D_, DH_, nullptr, 1 << 30, wkT, DH_, (long)D_ * DH_,
      qt, H_ * D_, D_, 0, DH_);

  // 3) fused flash attention + combine
  fused_attn<<<dim3(B_, 2), 1024, 0, stream>>>(x, buffer, qt, part_a, ml);
  combine_k<<<B_ * H_, 256, 0, stream>>>(part_a, ml, vt);

  // 4) o0[b,h*128+d] = sum_e vt[b,h,e] * Wv[h*128+d,e]  (K=2048, per-head n)
  gemm_mfma<false><<<dim3(2, 16, 8), 256, 0, stream>>>(
      vt, H_ * D_, D_, nullptr, 1 << 30, Wv, D_, (long)DH_ * D_,
      partg, D_, DH_, S, 256);
  reduce_add_k<<<512, 256, 0, stream>>>(partg, 8, S, S, o0);

  // 5) o1 = o0 @ Wo.T
  gemm_mfma<false><<<dim3(32, 1, 8), 256, 0, stream>>>(
      o0, D_, 0, nullptr, 1 << 30, Wo, D_, 0, partg, D_, 0, S, 256);
  reduce_add_k<<<512, 256, 0, stream>>>(partg, 8, S, S, o1);

  // 6) gate: z = concat(x,o1) @ Wg.T + bg   (K=4096, A-switch at 2048)
  gemm_mfma<false><<<dim3(32, 1, 8), 256, 0, stream>>>(
      x, D_, 0, o1, D_, Wg, 2 * D_, 0, partg, D_, 0, S, 512);
  gate_final_k<<<1024, 256, 0, stream>>>(partg, bg, x, o1, y);

  (void)in_sizes; (void)n_in; (void)out_size; (void)ws_size;
}

// Round 8
// 252.210 us; speedup vs baseline: 1.2991x; 1.2991x over previous
//
#include <hip/hip_runtime.h>
#include <hip/hip_bf16.h>
#include <math.h>

// Shapes (fixed by the reference)
#define B_   128
#define W_   512
#define D_   2048
#define H_   16
#define DH_  128

typedef __attribute__((ext_vector_type(4))) float f32x4;
typedef __attribute__((ext_vector_type(8))) short bf16x8;

typedef const __attribute__((address_space(1))) void* gvp;
typedef __attribute__((address_space(3))) void* lvp;

__device__ inline short f2bf(float f) {
  union { __hip_bfloat16 h; short s; } u;
  u.h = __float2bfloat16(f);
  return u.s;
}
__device__ inline float bf2f(unsigned short u) {
  return __uint_as_float(((unsigned)u) << 16);
}

// raw barrier: drain LDS ops but NOT in-flight global_load_lds (vmcnt).
#define LGKM_BARRIER() do {                                   \
    asm volatile("s_waitcnt lgkmcnt(0)" ::: "memory");        \
    __builtin_amdgcn_sched_barrier(0);                        \
    __builtin_amdgcn_s_barrier();                             \
    __builtin_amdgcn_sched_barrier(0);                        \
  } while (0)

// ---------------------------------------------------------------------------
// bf16 MFMA GEMM, M = 128 always.  C[m,n] = sum_k A[m,k] * B[n,k].
// (unchanged from R3/R6)
// ---------------------------------------------------------------------------
template<bool BBF16>
__global__ __launch_bounds__(256) void gemm_mfma(
    const float* __restrict__ A, int a_rs, long a_hs,
    const float* __restrict__ A2, int a2_k,
    const void* __restrict__ Bv, int b_rs, long b_hs,
    float* __restrict__ C, int c_rs, long c_hs, long c_ks,
    int Kblk)
{
  __shared__ char sm[2][24576];

  const int t  = threadIdx.x;
  const int w  = t >> 6, l = t & 63, lo = l & 15, hi = l >> 4;
  const int wm = w >> 1, wn = w & 1;
  const int n0   = blockIdx.x * 64;
  const int head = blockIdx.y;
  const int ks   = blockIdx.z;
  const int kbeg = ks * Kblk;
  const int nit  = Kblk >> 6;

  const float* Ab;
  {
    const float* base = A;
    int koff = kbeg;
    if (A2 && kbeg >= a2_k) { base = A2; koff = kbeg - a2_k; }
    Ab = base + head * a_hs + koff;
  }
  const float*          Bf = (const float*)Bv          + (BBF16 ? 0 : head * b_hs + (long)n0 * b_rs + kbeg);
  const unsigned short* Bh = (const unsigned short*)Bv + (BBF16 ? head * b_hs + (long)n0 * b_rs + kbeg : 0);

  const int ar = t >> 2;
  const int ak = (t & 3) * 16;

  f32x4 acc[4][2] = {};

  auto load_tiles = [&](int it, float4* ar4, float4* br4) {
    const float* Ait = Ab + it * 64;
#pragma unroll
    for (int p = 0; p < 2; ++p) {
      const float* src = Ait + (long)(p * 64 + ar) * a_rs + ak;
#pragma unroll
      for (int qq = 0; qq < 4; ++qq) ar4[p * 4 + qq] = *(const float4*)(src + qq * 4);
    }
    if (BBF16) {
      const char* src = (const char*)(Bh + (long)ar * b_rs + it * 64 + ak);
      br4[0] = *(const float4*)(src);
      br4[1] = *(const float4*)(src + 16);
    } else {
      const float* src = Bf + (long)ar * b_rs + it * 64 + ak;
#pragma unroll
      for (int qq = 0; qq < 4; ++qq) br4[qq] = *(const float4*)(src + qq * 4);
    }
  };

  auto write_tiles = [&](int buf, const float4* ar4, const float4* br4) {
    char* As = sm[buf];
    char* Bs = sm[buf] + 16384;
#pragma unroll
    for (int p = 0; p < 2; ++p) {
      int m = p * 64 + ar;
      int base = m * 128 + ak * 2;
      int swz = (m & 7) << 4;
#pragma unroll
      for (int h2 = 0; h2 < 2; ++h2) {
        bf16x8 v;
        const float* f = (const float*)(ar4 + p * 4);
#pragma unroll
        for (int j = 0; j < 8; ++j) v[j] = f2bf(f[h2 * 8 + j]);
        *(bf16x8*)(As + ((base + h2 * 16) ^ swz)) = v;
      }
    }
    {
      int n = ar;
      int base = n * 128 + ak * 2;
      int swz = (n & 7) << 4;
      if (BBF16) {
#pragma unroll
        for (int h2 = 0; h2 < 2; ++h2)
          *(bf16x8*)(Bs + ((base + h2 * 16) ^ swz)) = ((const bf16x8*)br4)[h2];
      } else {
#pragma unroll
        for (int h2 = 0; h2 < 2; ++h2) {
          bf16x8 v;
          const float* f = (const float*)br4;
#pragma unroll
          for (int j = 0; j < 8; ++j) v[j] = f2bf(f[h2 * 8 + j]);
          *(bf16x8*)(Bs + ((base + h2 * 16) ^ swz)) = v;
        }
      }
    }
  };

  auto compute = [&](int buf) {
    const char* As = sm[buf];
    const char* Bs = sm[buf] + 16384;
#pragma unroll
    for (int kk = 0; kk < 2; ++kk) {
      bf16x8 af[4], bfr[2];
#pragma unroll
      for (int mi = 0; mi < 4; ++mi) {
        int m = wm * 64 + mi * 16 + lo;
        af[mi] = *(const bf16x8*)(As + ((m * 128 + (kk * 32 + hi * 8) * 2) ^ ((m & 7) << 4)));
      }
#pragma unroll
      for (int ni = 0; ni < 2; ++ni) {
        int n = wn * 32 + ni * 16 + lo;
        bfr[ni] = *(const bf16x8*)(Bs + ((n * 128 + (kk * 32 + hi * 8) * 2) ^ ((n & 7) << 4)));
      }
#pragma unroll
      for (int mi = 0; mi < 4; ++mi)
#pragma unroll
        for (int ni = 0; ni < 2; ++ni)
          acc[mi][ni] = __builtin_amdgcn_mfma_f32_16x16x32_bf16(af[mi], bfr[ni], acc[mi][ni], 0, 0, 0);
    }
  };

  float4 ar4[8], br4[4];
  load_tiles(0, ar4, br4);
  write_tiles(0, ar4, br4);
  __syncthreads();
  for (int it = 0; it < nit; ++it) {
    float4 na[8], nb[4];
    if (it + 1 < nit) load_tiles(it + 1, na, nb);
    compute(it & 1);
    if (it + 1 < nit) write_tiles((it + 1) & 1, na, nb);
    __syncthreads();
  }

  float* Cb = C + c_ks * ks + c_hs * head + n0;
#pragma unroll
  for (int mi = 0; mi < 4; ++mi)
#pragma unroll
    for (int ni = 0; ni < 2; ++ni)
#pragma unroll
      for (int r = 0; r < 4; ++r)
        Cb[(long)(wm * 64 + mi * 16 + hi * 4 + r) * c_rs + (wn * 32 + ni * 16 + lo)] = acc[mi][ni][r];
}

// ---------------------------------------------------------------------------
// WkT[h][e][d] (bf16) = Wk[h*128+d][e].  (unchanged)
// ---------------------------------------------------------------------------
__global__ __launch_bounds__(256) void transpose_wk(
    const float* __restrict__ Wk, unsigned short* __restrict__ WkT)
{
  __shared__ float tile[64][68];
  const int t  = threadIdx.x;
  const int e0 = blockIdx.x * 64;
  const int d0 = blockIdx.y * 64;
  const int h  = blockIdx.z;
  {
    int d = t >> 2, eq = (t & 3) * 16;
    const float* src = Wk + (long)(h * DH_ + d0 + d) * D_ + e0 + eq;
#pragma unroll
    for (int qq = 0; qq < 4; ++qq)
      *(float4*)&tile[d][eq + qq * 4] = *(const float4*)(src + qq * 4);
  }
  __syncthreads();
  {
    int e = t >> 2, dq = (t & 3) * 16;
    unsigned short* dst = WkT + ((long)h * D_ + e0 + e) * DH_ + d0 + dq;
    bf16x8 v0, v1;
#pragma unroll
    for (int j = 0; j < 8; ++j) v0[j] = f2bf(tile[dq + j][e]);
#pragma unroll
    for (int j = 0; j < 8; ++j) v1[j] = f2bf(tile[dq + 8 + j][e]);
    *(bf16x8*)dst = v0;
    *(bf16x8*)(dst + 8) = v1;
  }
}

// ---------------------------------------------------------------------------
__global__ void reduce_add_k(const float* __restrict__ part, int ns, long stride,
                             long n, float* __restrict__ out)
{
  for (long i = (long)blockIdx.x * blockDim.x + threadIdx.x; i < n;
       i += (long)gridDim.x * blockDim.x) {
    float s = 0.f;
    for (int k = 0; k < ns; ++k) s += part[k * stride + i];
    out[i] = s;
  }
}

// ---------------------------------------------------------------------------
// Fused flash attention v3b = R6 structure (fp32 KV via global_load_lds,
// 8-row double-buffered tiles, plain partial stores, 4-wave softmax) with
// ONE change: the logits B-frag fp32->bf16 conversion uses v_perm
// truncation (1 instr per bf16 pair) instead of 8 software-RNE chains —
// removes ~150-200 VALU from the dependent path before each MFMA.
// ---------------------------------------------------------------------------
__global__ __launch_bounds__(1024, 4) void fused_attn(
    const float* __restrict__ x, const float* __restrict__ buffer,
    const float* __restrict__ qt, unsigned short* __restrict__ part,
    float* __restrict__ ml)
{
  __shared__ float kv[2 * 8 * 2048];   // 128 KiB, two 8-row fp32 tiles
  __shared__ float lacc[16][8][16];    // partials [wave][s][h], 8 KiB
  __shared__ float pbuf[16][8];        // P fp32 [h][s]
  __shared__ float sbuf[16];           // per-h rescale factor

  const int b    = blockIdx.x;
  const int half = blockIdx.y;
  const int t    = threadIdx.x;
  const int w    = t >> 6;
  const int lane = t & 63;
  const int lo   = lane & 15;
  const int hi   = lane >> 4;
  const char* kvb = (const char*)kv;

  // q~ A-frags for this wave's e-band (scale folded in), bf16 RNE (once)
  bf16x8 afrag[4];
  {
    const float* qrow = qt + ((long)b * H_ + lo) * D_;
    const float sc = 0.088388347648318447f;  // 1/sqrt(128)
#pragma unroll
    for (int kk = 0; kk < 4; ++kk) {
      int e0 = w * 128 + kk * 32 + hi * 8;
#pragma unroll
      for (int j = 0; j < 8; ++j) afrag[kk][j] = f2bf(qrow[e0 + j] * sc);
    }
  }

  float accE[16][2];
#pragma unroll
  for (int h = 0; h < 16; ++h) { accE[h][0] = 0.f; accE[h][1] = 0.f; }
  float m_run = -1e30f, l_run = 0.f;   // valid in waves 0-3

  auto stage = [&](int sb, int tl) {
#pragma unroll
    for (int r = 0; r < 4; ++r) {
      int s = r * 2 + (w >> 3);
      int inrow = (w & 7) * 1024 + lane * 16;
      int srco = inrow ^ (s << 4);
      int s_glob = half * 256 + tl * 8 + s;
      const float* row = (s_glob < W_ - 1)
          ? buffer + (((long)(b * W_ + s_glob + 1)) << 11)
          : x + ((long)b << 11);
      __builtin_amdgcn_global_load_lds(
          (gvp)(row + (srco >> 2)),
          (lvp)(kv + sb * 16384 + r * 4096 + w * 256), 16, 0, 0);
    }
  };

  stage(0, 0);
  __syncthreads();

  for (int tile = 0; tile < 32; ++tile) {
    const int buf  = tile & 1;
    const int bufo = buf * 65536;

    // issue next tile's loads NOW; they stay in flight across the whole
    // iteration (B1/B2 do not drain vmcnt), drained at the loop-end B3.
    if (tile + 1 < 32) stage(buf ^ 1, tile + 1);

    // ---- partial logits over this wave's e-band (MFMA, v_perm pack)
    {
      f32x4 c4 = {0.f, 0.f, 0.f, 0.f};
      const int srow = lo & 7;   // cols 8..15 duplicate rows 0..7
#pragma unroll
      for (int kk = 0; kk < 4; ++kk) {
        unsigned B0 = (unsigned)(srow * 8192 + (w * 128 + kk * 32 + hi * 8) * 4);
        unsigned o1 = B0 ^ (unsigned)(srow << 4);
        float4 f1 = *(const float4*)(kvb + bufo + o1);
        float4 f2 = *(const float4*)(kvb + bufo + (o1 ^ 16u));
        // truncation pack: u = (hi16(odd)<<16) | hi16(even), 1 v_perm each
        unsigned u[4];
        u[0] = __builtin_amdgcn_perm(__float_as_uint(f1.y), __float_as_uint(f1.x), 0x07060302u);
        u[1] = __builtin_amdgcn_perm(__float_as_uint(f1.w), __float_as_uint(f1.z), 0x07060302u);
        u[2] = __builtin_amdgcn_perm(__float_as_uint(f2.y), __float_as_uint(f2.x), 0x07060302u);
        u[3] = __builtin_amdgcn_perm(__float_as_uint(f2.w), __float_as_uint(f2.z), 0x07060302u);
        bf16x8 bf;
        __builtin_memcpy(&bf, u, 16);
        c4 = __builtin_amdgcn_mfma_f32_16x16x32_bf16(afrag[kk], bf, c4, 0, 0, 0);
      }
      // D[h=hi*4+r][s=lo]; store [w][s][h] -> contiguous in r: one b128
      if (lo < 8) *(f32x4*)&lacc[w][lo][hi * 4] = c4;
    }
    LGKM_BARRIER();                    // B1: partials visible

    // ---- reduce + online softmax: waves 0-3, wave wr owns h = wr*4+hi
    if (w < 4) {
      const int h = w * 4 + hi;
      const int s = lo & 7;            // lanes lo 8-15 duplicate lo 0-7
      float v = 0.f;
#pragma unroll
      for (int ww = 0; ww < 16; ++ww) v += lacc[ww][s][h];
      float mt = v;
      mt = fmaxf(mt, __shfl_xor(mt, 1));
      mt = fmaxf(mt, __shfl_xor(mt, 2));
      mt = fmaxf(mt, __shfl_xor(mt, 4));
      float m_new = fmaxf(m_run, mt);
      float scl = __expf(m_run - m_new);
      float p = __expf(v - m_new);
      float ps = p;
      ps += __shfl_xor(ps, 1);
      ps += __shfl_xor(ps, 2);
      ps += __shfl_xor(ps, 4);
      l_run = l_run * scl + ps;
      m_run = m_new;
      if (lo < 8) pbuf[h][s] = p;
      if (lo == 0) sbuf[h] = scl;
    }
    LGKM_BARRIER();                    // B2: pbuf/sbuf ready

    // ---- rescale + PV (fp32 VALU). lane owns e = 128w + 2*lane (+1).
    const unsigned ebyte = (unsigned)((w * 128 + lane * 2) * 4);
    float2 kvp[8];
#pragma unroll
    for (int s = 0; s < 8; ++s) {
      unsigned Bx = (unsigned)(s * 8192) + ebyte;
      kvp[s] = *(const float2*)(kvb + bufo + (Bx ^ (unsigned)(s << 4)));
    }
#pragma unroll
    for (int h = 0; h < 16; ++h) {
      float scl = sbuf[h];
      float a0 = accE[h][0] * scl, a1 = accE[h][1] * scl;
      float4 pA = *(const float4*)&pbuf[h][0];
      float4 pB = *(const float4*)&pbuf[h][4];
      a0 += pA.x * kvp[0].x + pA.y * kvp[1].x + pA.z * kvp[2].x + pA.w * kvp[3].x
          + pB.x * kvp[4].x + pB.y * kvp[5].x + pB.z * kvp[6].x + pB.w * kvp[7].x;
      a1 += pA.x * kvp[0].y + pA.y * kvp[1].y + pA.z * kvp[2].y + pA.w * kvp[3].y
          + pB.x * kvp[4].y + pB.y * kvp[5].y + pB.z * kvp[6].y + pB.w * kvp[7].y;
      accE[h][0] = a0; accE[h][1] = a1;
    }
    __syncthreads();                   // B3: vmcnt(0) drain -> tile t+1 ready
  }

  // ---- epilogue: unnormalized acc (bf16) + (m,l)
  {
    long base = ((long)half * B_ + b) * H_;
#pragma unroll
    for (int h = 0; h < 16; ++h) {
      long idx = (base + h) * D_ + w * 128 + lane * 2;
      unsigned u0 = (unsigned short)f2bf(accE[h][0]);
      unsigned u1 = (unsigned short)f2bf(accE[h][1]);
      *(unsigned*)(part + idx) = u0 | (u1 << 16);
    }
    if (w < 4 && lo == 0) {
      ml[(base + w * 4 + hi) * 2 + 0] = m_run;
      ml[(base + w * 4 + hi) * 2 + 1] = l_run;
    }
  }
}

// ---------------------------------------------------------------------------
__global__ __launch_bounds__(256) void combine_k(
    const unsigned short* __restrict__ part, const float* __restrict__ ml,
    float* __restrict__ vt)
{
  const int bh = blockIdx.x;
  const float m0 = ml[bh * 2],          l0 = ml[bh * 2 + 1];
  const float m1 = ml[(2048 + bh) * 2], l1 = ml[(2048 + bh) * 2 + 1];
  const float M  = fmaxf(m0, m1);
  const float w0 = __expf(m0 - M), w1 = __expf(m1 - M);
  const float inv = 1.0f / (w0 * l0 + w1 * l1);
  const unsigned short* p0 = part + (long)bh * D_;
  const unsigned short* p1 = part + (long)(2048 + bh) * D_;
  float* out = vt + (long)bh * D_;

  const int e = threadIdx.x * 8;
  ushort4 a1 = *(const ushort4*)(p0 + e);
  ushort4 a2 = *(const ushort4*)(p0 + e + 4);
  ushort4 b1 = *(const ushort4*)(p1 + e);
  ushort4 b2 = *(const ushort4*)(p1 + e + 4);
  float oa[8], ob[8];
  oa[0]=bf2f(a1.x); oa[1]=bf2f(a1.y); oa[2]=bf2f(a1.z); oa[3]=bf2f(a1.w);
  oa[4]=bf2f(a2.x); oa[5]=bf2f(a2.y); oa[6]=bf2f(a2.z); oa[7]=bf2f(a2.w);
  ob[0]=bf2f(b1.x); ob[1]=bf2f(b1.y); ob[2]=bf2f(b1.z); ob[3]=bf2f(b1.w);
  ob[4]=bf2f(b2.x); ob[5]=bf2f(b2.y); ob[6]=bf2f(b2.z); ob[7]=bf2f(b2.w);
#pragma unroll
  for (int j = 0; j < 8; ++j) out[e + j] = (w0 * oa[j] + w1 * ob[j]) * inv;
}

// ---------------------------------------------------------------------------
__global__ __launch_bounds__(256) void gate_final_k(
    const float* __restrict__ part, const float* __restrict__ bg,
    const float* __restrict__ x, const float* __restrict__ out1,
    float* __restrict__ y)
{
  const long i = (long)blockIdx.x * 256 + threadIdx.x;
  float z = bg[i & (D_ - 1)];
#pragma unroll
  for (int k = 0; k < 8; ++k) z += part[(long)k * (B_ * D_) + i];
  const float g = 1.0f / (1.0f + expf(-z));
  y[i] = x[i] + g * out1[i];
}

// ---------------------------------------------------------------------------
extern "C" void kernel_launch(void* const* d_in, const int* in_sizes, int n_in,
                              void* d_out, int out_size, void* d_ws, size_t ws_size,
                              hipStream_t stream)
{
  const float* x      = (const float*)d_in[0];
  const float* buffer = (const float*)d_in[1];
  const float* Wq     = (const float*)d_in[2];
  const float* Wk     = (const float*)d_in[3];
  const float* Wv     = (const float*)d_in[4];
  const float* Wo     = (const float*)d_in[5];
  const float* Wg     = (const float*)d_in[6];
  const float* bg     = (const float*)d_in[7];
  float* y = (float*)d_out;

  // workspace layout (float units)
  float* ws    = (float*)d_ws;
  float* q     = ws;                        // 262144
  float* qt    = ws + 262144;               // 4194304 (vt aliases after fused)
  float* vt    = qt;
  unsigned short* part_a = (unsigned short*)(ws + 4456448); // 8388608 bf16
  float* ml    = ws + 8650752;              // 8192
  float* o0    = ws + 8658944;              // 262144
  float* o1    = ws + 8921088;              // 262144
  float* partg = ws + 9183232;              // 8 * 262144 = 2097152
  unsigned short* wkT = (unsigned short*)(ws + 11280384);   // 16*2048*128 bf16

  const long S = (long)B_ * D_;

  // 0) WkT[h][e][d] bf16
  transpose_wk<<<dim3(32, 2, 16), 256, 0, stream>>>(Wk, wkT);

  // 1) q = x @ Wq.T   (K=2048, ksplit 8)
  gemm_mfma<false><<<dim3(32, 1, 8), 256, 0, stream>>>(
      x, D_, 0, nullptr, 1 << 30, Wq, D_, 0, partg, D_, 0, S, 256);
  reduce_add_k<<<512, 256, 0, stream>>>(partg, 8, S, S, q);

  // 2) qt[b,h,e] = sum_d q[b,h*128+d] * WkT[h][e][d]   (K=128, per-head)
  gemm_mfma<true><<<dim3(32, 16, 1), 256, 0, stream>>>(
      q, D_, DH_, nullptr, 1 << 30, wkT, DH_, (long)D_ * DH_,
      qt, H_ * D_, D_, 0, DH_);

  // 3) fused flash attention + combine
  fused_attn<<<dim3(B_, 2), 1024, 0, stream>>>(x, buffer, qt, part_a, ml);
  combine_k<<<B_ * H_, 256, 0, stream>>>(part_a, ml, vt);

  // 4) o0[b,h*128+d] = sum_e vt[b,h,e] * Wv[h*128+d,e]  (K=2048, per-head n)
  gemm_mfma<false><<<dim3(2, 16, 8), 256, 0, stream>>>(
      vt, H_ * D_, D_, nullptr, 1 << 30, Wv, D_, (long)DH_ * D_,
      partg, D_, DH_, S, 256);
  reduce_add_k<<<512, 256, 0, stream>>>(partg, 8, S, S, o0);

  // 5) o1 = o0 @ Wo.T
  gemm_mfma<false><<<dim3(32, 1, 8), 256, 0, stream>>>(
      o0, D_, 0, nullptr, 1 << 30, Wo, D_, 0, partg, D_, 0, S, 256);
  reduce_add_k<<<512, 256, 0, stream>>>(partg, 8, S, S, o1);

  // 6) gate: z = concat(x,o1) @ Wg.T + bg   (K=4096, A-switch at 2048)
  gemm_mfma<false><<<dim3(32, 1, 8), 256, 0, stream>>>(
      x, D_, 0, o1, D_, Wg, 2 * D_, 0, partg, D_, 0, S, 512);
  gate_final_k<<<1024, 256, 0, stream>>>(partg, bg, x, o1, y);

  (void)in_sizes; (void)n_in; (void)out_size; (void)ws_size;
}

// Round 9
// 244.755 us; speedup vs baseline: 1.3387x; 1.0305x over previous
//
#include <hip/hip_runtime.h>
#include <hip/hip_bf16.h>
#include <math.h>

// Shapes (fixed by the reference)
#define B_   128
#define W_   512
#define D_   2048
#define H_   16
#define DH_  128

typedef __attribute__((ext_vector_type(4))) float f32x4;
typedef __attribute__((ext_vector_type(8))) short bf16x8;

typedef const __attribute__((address_space(1))) void* gvp;
typedef __attribute__((address_space(3))) void* lvp;

__device__ inline short f2bf(float f) {
  union { __hip_bfloat16 h; short s; } u;
  u.h = __float2bfloat16(f);
  return u.s;
}
__device__ inline float bf2f(unsigned short u) {
  return __uint_as_float(((unsigned)u) << 16);
}

// raw barrier: drain LDS ops but NOT in-flight global_load_lds (vmcnt).
#define LGKM_BARRIER() do {                                   \
    asm volatile("s_waitcnt lgkmcnt(0)" ::: "memory");        \
    __builtin_amdgcn_sched_barrier(0);                        \
    __builtin_amdgcn_s_barrier();                             \
    __builtin_amdgcn_sched_barrier(0);                        \
  } while (0)

// ---------------------------------------------------------------------------
// bf16 MFMA GEMM, M = 128 always.  C[m,n] = sum_k A[m,k] * B[n,k].
// AMODE 0: A fp32 (+ optional A2 concat switch at a2_k).
// AMODE 1: A = part_a (bf16 two-half flash partials, via A ptr) combined with
//          ml (via A2 ptr): val = (w0*p0 + w1*p1) * inv  — combine_k folded.
// ---------------------------------------------------------------------------
template<bool BBF16, int AMODE>
__global__ __launch_bounds__(256) void gemm_mfma(
    const float* __restrict__ A, int a_rs, long a_hs,
    const float* __restrict__ A2, int a2_k,
    const void* __restrict__ Bv, int b_rs, long b_hs,
    float* __restrict__ C, int c_rs, long c_hs, long c_ks,
    int Kblk)
{
  __shared__ char sm[2][24576];

  const int t  = threadIdx.x;
  const int w  = t >> 6, l = t & 63, lo = l & 15, hi = l >> 4;
  const int wm = w >> 1, wn = w & 1;
  const int n0   = blockIdx.x * 64;
  const int head = blockIdx.y;
  const int ks   = blockIdx.z;
  const int kbeg = ks * Kblk;
  const int nit  = Kblk >> 6;

  const float* Ab = nullptr;
  if (AMODE == 0) {
    const float* base = A;
    int koff = kbeg;
    if (A2 && kbeg >= a2_k) { base = A2; koff = kbeg - a2_k; }
    Ab = base + head * a_hs + koff;
  }
  const float*          Bf = (const float*)Bv          + (BBF16 ? 0 : head * b_hs + (long)n0 * b_rs + kbeg);
  const unsigned short* Bh = (const unsigned short*)Bv + (BBF16 ? head * b_hs + (long)n0 * b_rs + kbeg : 0);

  const int ar = t >> 2;
  const int ak = (t & 3) * 16;

  f32x4 acc[4][2] = {};

  auto load_tiles = [&](int it, float4* ar4, float4* br4) {
    if (AMODE == 0) {
      const float* Ait = Ab + it * 64;
#pragma unroll
      for (int p = 0; p < 2; ++p) {
        const float* src = Ait + (long)(p * 64 + ar) * a_rs + ak;
#pragma unroll
        for (int qq = 0; qq < 4; ++qq) ar4[p * 4 + qq] = *(const float4*)(src + qq * 4);
      }
    } else {
      // folded combine: A = part_a (ushort), A2 = ml (float)
      const unsigned short* pa = (const unsigned short*)A;
      const float* mlp = A2;
      const int col = kbeg + it * 64 + ak;
#pragma unroll
      for (int p = 0; p < 2; ++p) {
        int m  = p * 64 + ar;
        int bh = m * 16 + head;
        float m0 = mlp[bh * 2],              l0 = mlp[bh * 2 + 1];
        float m1 = mlp[(2048 + bh) * 2],     l1 = mlp[(2048 + bh) * 2 + 1];
        float M  = fmaxf(m0, m1);
        float w0 = __expf(m0 - M), w1 = __expf(m1 - M);
        float inv = 1.0f / (w0 * l0 + w1 * l1);
        w0 *= inv; w1 *= inv;
        const unsigned short* r0 = pa + (long)bh * D_ + col;
        const unsigned short* r1 = r0 + (long)B_ * H_ * D_;
#pragma unroll
        for (int q2 = 0; q2 < 2; ++q2) {
          bf16x8 a0 = *(const bf16x8*)(r0 + q2 * 8);
          bf16x8 a1 = *(const bf16x8*)(r1 + q2 * 8);
          float out[8];
#pragma unroll
          for (int j = 0; j < 8; ++j)
            out[j] = w0 * bf2f((unsigned short)a0[j]) + w1 * bf2f((unsigned short)a1[j]);
          ar4[p * 4 + q2 * 2]     = make_float4(out[0], out[1], out[2], out[3]);
          ar4[p * 4 + q2 * 2 + 1] = make_float4(out[4], out[5], out[6], out[7]);
        }
      }
    }
    if (BBF16) {
      const char* src = (const char*)(Bh + (long)ar * b_rs + it * 64 + ak);
      br4[0] = *(const float4*)(src);
      br4[1] = *(const float4*)(src + 16);
    } else {
      const float* src = Bf + (long)ar * b_rs + it * 64 + ak;
#pragma unroll
      for (int qq = 0; qq < 4; ++qq) br4[qq] = *(const float4*)(src + qq * 4);
    }
  };

  auto write_tiles = [&](int buf, const float4* ar4, const float4* br4) {
    char* As = sm[buf];
    char* Bs = sm[buf] + 16384;
#pragma unroll
    for (int p = 0; p < 2; ++p) {
      int m = p * 64 + ar;
      int base = m * 128 + ak * 2;
      int swz = (m & 7) << 4;
#pragma unroll
      for (int h2 = 0; h2 < 2; ++h2) {
        bf16x8 v;
        const float* f = (const float*)(ar4 + p * 4);
#pragma unroll
        for (int j = 0; j < 8; ++j) v[j] = f2bf(f[h2 * 8 + j]);
        *(bf16x8*)(As + ((base + h2 * 16) ^ swz)) = v;
      }
    }
    {
      int n = ar;
      int base = n * 128 + ak * 2;
      int swz = (n & 7) << 4;
      if (BBF16) {
#pragma unroll
        for (int h2 = 0; h2 < 2; ++h2)
          *(bf16x8*)(Bs + ((base + h2 * 16) ^ swz)) = ((const bf16x8*)br4)[h2];
      } else {
#pragma unroll
        for (int h2 = 0; h2 < 2; ++h2) {
          bf16x8 v;
          const float* f = (const float*)br4;
#pragma unroll
          for (int j = 0; j < 8; ++j) v[j] = f2bf(f[h2 * 8 + j]);
          *(bf16x8*)(Bs + ((base + h2 * 16) ^ swz)) = v;
        }
      }
    }
  };

  auto compute = [&](int buf) {
    const char* As = sm[buf];
    const char* Bs = sm[buf] + 16384;
#pragma unroll
    for (int kk = 0; kk < 2; ++kk) {
      bf16x8 af[4], bfr[2];
#pragma unroll
      for (int mi = 0; mi < 4; ++mi) {
        int m = wm * 64 + mi * 16 + lo;
        af[mi] = *(const bf16x8*)(As + ((m * 128 + (kk * 32 + hi * 8) * 2) ^ ((m & 7) << 4)));
      }
#pragma unroll
      for (int ni = 0; ni < 2; ++ni) {
        int n = wn * 32 + ni * 16 + lo;
        bfr[ni] = *(const bf16x8*)(Bs + ((n * 128 + (kk * 32 + hi * 8) * 2) ^ ((n & 7) << 4)));
      }
#pragma unroll
      for (int mi = 0; mi < 4; ++mi)
#pragma unroll
        for (int ni = 0; ni < 2; ++ni)
          acc[mi][ni] = __builtin_amdgcn_mfma_f32_16x16x32_bf16(af[mi], bfr[ni], acc[mi][ni], 0, 0, 0);
    }
  };

  float4 ar4[8], br4[4];
  load_tiles(0, ar4, br4);
  write_tiles(0, ar4, br4);
  __syncthreads();
  for (int it = 0; it < nit; ++it) {
    float4 na[8], nb[4];
    if (it + 1 < nit) load_tiles(it + 1, na, nb);
    compute(it & 1);
    if (it + 1 < nit) write_tiles((it + 1) & 1, na, nb);
    __syncthreads();
  }

  float* Cb = C + c_ks * ks + c_hs * head + n0;
#pragma unroll
  for (int mi = 0; mi < 4; ++mi)
#pragma unroll
    for (int ni = 0; ni < 2; ++ni)
#pragma unroll
      for (int r = 0; r < 4; ++r)
        Cb[(long)(wm * 64 + mi * 16 + hi * 4 + r) * c_rs + (wn * 32 + ni * 16 + lo)] = acc[mi][ni][r];
}

// ---------------------------------------------------------------------------
// WkT[h][e][d] (bf16) = Wk[h*128+d][e].  (unchanged)
// ---------------------------------------------------------------------------
__global__ __launch_bounds__(256) void transpose_wk(
    const float* __restrict__ Wk, unsigned short* __restrict__ WkT)
{
  __shared__ float tile[64][68];
  const int t  = threadIdx.x;
  const int e0 = blockIdx.x * 64;
  const int d0 = blockIdx.y * 64;
  const int h  = blockIdx.z;
  {
    int d = t >> 2, eq = (t & 3) * 16;
    const float* src = Wk + (long)(h * DH_ + d0 + d) * D_ + e0 + eq;
#pragma unroll
    for (int qq = 0; qq < 4; ++qq)
      *(float4*)&tile[d][eq + qq * 4] = *(const float4*)(src + qq * 4);
  }
  __syncthreads();
  {
    int e = t >> 2, dq = (t & 3) * 16;
    unsigned short* dst = WkT + ((long)h * D_ + e0 + e) * DH_ + d0 + dq;
    bf16x8 v0, v1;
#pragma unroll
    for (int j = 0; j < 8; ++j) v0[j] = f2bf(tile[dq + j][e]);
#pragma unroll
    for (int j = 0; j < 8; ++j) v1[j] = f2bf(tile[dq + 8 + j][e]);
    *(bf16x8*)dst = v0;
    *(bf16x8*)(dst + 8) = v1;
  }
}

// ---------------------------------------------------------------------------
__global__ void reduce_add_k(const float* __restrict__ part, int ns, long stride,
                             long n, float* __restrict__ out)
{
  for (long i = (long)blockIdx.x * blockDim.x + threadIdx.x; i < n;
       i += (long)gridDim.x * blockDim.x) {
    float s = 0.f;
    for (int k = 0; k < ns; ++k) s += part[k * stride + i];
    out[i] = s;
  }
}

// ---------------------------------------------------------------------------
// Fused flash attention v5 = R6/R8 structure with:
//   - 16-wave h-parallel online softmax (wave w owns head w; 2 LDS reads +
//     6 shfl per lane) replacing the 4-wave serial reduce
//   - PV's kv reads hoisted before B1 (overlap the softmax barriers)
//   - lacc padded [16][9][20] (b128 store aligned; column read <=8-way)
// ---------------------------------------------------------------------------
__global__ __launch_bounds__(1024, 4) void fused_attn(
    const float* __restrict__ x, const float* __restrict__ buffer,
    const float* __restrict__ qt, unsigned short* __restrict__ part,
    float* __restrict__ ml)
{
  __shared__ float kv[2 * 8 * 2048];   // 128 KiB, two 8-row fp32 tiles
  __shared__ float lacc[16][9][20];    // partials [wave][s][h], padded
  __shared__ float pbuf[16][8];        // P fp32 [h][s]
  __shared__ float sbuf[16];           // per-h rescale factor

  const int b    = blockIdx.x;
  const int half = blockIdx.y;
  const int t    = threadIdx.x;
  const int w    = t >> 6;
  const int lane = t & 63;
  const int lo   = lane & 15;
  const int hi   = lane >> 4;
  const char* kvb = (const char*)kv;

  // q~ A-frags for this wave's e-band (scale folded in), bf16 RNE (once)
  bf16x8 afrag[4];
  {
    const float* qrow = qt + ((long)b * H_ + lo) * D_;
    const float sc = 0.088388347648318447f;  // 1/sqrt(128)
#pragma unroll
    for (int kk = 0; kk < 4; ++kk) {
      int e0 = w * 128 + kk * 32 + hi * 8;
#pragma unroll
      for (int j = 0; j < 8; ++j) afrag[kk][j] = f2bf(qrow[e0 + j] * sc);
    }
  }

  float accE[16][2];
#pragma unroll
  for (int h = 0; h < 16; ++h) { accE[h][0] = 0.f; accE[h][1] = 0.f; }
  float m_run = -1e30f, l_run = 0.f;   // per wave: head w's online state

  auto stage = [&](int sb, int tl) {
#pragma unroll
    for (int r = 0; r < 4; ++r) {
      int s = r * 2 + (w >> 3);
      int inrow = (w & 7) * 1024 + lane * 16;
      int srco = inrow ^ (s << 4);
      int s_glob = half * 256 + tl * 8 + s;
      const float* row = (s_glob < W_ - 1)
          ? buffer + (((long)(b * W_ + s_glob + 1)) << 11)
          : x + ((long)b << 11);
      __builtin_amdgcn_global_load_lds(
          (gvp)(row + (srco >> 2)),
          (lvp)(kv + sb * 16384 + r * 4096 + w * 256), 16, 0, 0);
    }
  };

  stage(0, 0);
  __syncthreads();

  for (int tile = 0; tile < 32; ++tile) {
    const int buf  = tile & 1;
    const int bufo = buf * 65536;

    // issue next tile's loads NOW; they stay in flight across the whole
    // iteration (B1/B2 do not drain vmcnt), drained at the loop-end B3.
    if (tile + 1 < 32) stage(buf ^ 1, tile + 1);

    // ---- partial logits over this wave's e-band (MFMA, v_perm pack)
    {
      f32x4 c4 = {0.f, 0.f, 0.f, 0.f};
      const int srow = lo & 7;   // cols 8..15 duplicate rows 0..7
#pragma unroll
      for (int kk = 0; kk < 4; ++kk) {
        unsigned B0 = (unsigned)(srow * 8192 + (w * 128 + kk * 32 + hi * 8) * 4);
        unsigned o1 = B0 ^ (unsigned)(srow << 4);
        float4 f1 = *(const float4*)(kvb + bufo + o1);
        float4 f2 = *(const float4*)(kvb + bufo + (o1 ^ 16u));
        unsigned u[4];
        u[0] = __builtin_amdgcn_perm(__float_as_uint(f1.y), __float_as_uint(f1.x), 0x07060302u);
        u[1] = __builtin_amdgcn_perm(__float_as_uint(f1.w), __float_as_uint(f1.z), 0x07060302u);
        u[2] = __builtin_amdgcn_perm(__float_as_uint(f2.y), __float_as_uint(f2.x), 0x07060302u);
        u[3] = __builtin_amdgcn_perm(__float_as_uint(f2.w), __float_as_uint(f2.z), 0x07060302u);
        bf16x8 bf;
        __builtin_memcpy(&bf, u, 16);
        c4 = __builtin_amdgcn_mfma_f32_16x16x32_bf16(afrag[kk], bf, c4, 0, 0, 0);
      }
      // D[h=hi*4+r][s=lo]; store [w][s][h] contiguous in r: one b128
      if (lo < 8) *(f32x4*)&lacc[w][lo][hi * 4] = c4;
    }

    // ---- hoisted PV kv reads (need only the tile, overlap softmax wait)
    float2 kvp[8];
    {
      const unsigned ebyte = (unsigned)((w * 128 + lane * 2) * 4);
#pragma unroll
      for (int s = 0; s < 8; ++s) {
        unsigned Bx = (unsigned)(s * 8192) + ebyte;
        kvp[s] = *(const float2*)(kvb + bufo + (Bx ^ (unsigned)(s << 4)));
      }
    }
    LGKM_BARRIER();                    // B1: partials visible

    // ---- 16-wave online softmax: wave w owns head w
    {
      const int s   = lane & 7;
      const int wwg = lane >> 3;       // 8 groups of 2 waves
      float v = lacc[wwg][s][w] + lacc[wwg + 8][s][w];
      v += __shfl_xor(v, 8);
      v += __shfl_xor(v, 16);
      v += __shfl_xor(v, 32);          // now full e-sum, replicated per s
      float mt = v;
      mt = fmaxf(mt, __shfl_xor(mt, 1));
      mt = fmaxf(mt, __shfl_xor(mt, 2));
      mt = fmaxf(mt, __shfl_xor(mt, 4));
      float m_new = fmaxf(m_run, mt);
      float scl = __expf(m_run - m_new);
      float p = __expf(v - m_new);
      float ps = p;
      ps += __shfl_xor(ps, 1);
      ps += __shfl_xor(ps, 2);
      ps += __shfl_xor(ps, 4);
      l_run = l_run * scl + ps;
      m_run = m_new;
      if (lane < 8) pbuf[w][lane] = p;
      if (lane == 0) sbuf[w] = scl;
    }
    LGKM_BARRIER();                    // B2: pbuf/sbuf ready

    // ---- rescale + PV (fp32 VALU). lane owns e = 128w + 2*lane (+1).
#pragma unroll
    for (int h = 0; h < 16; ++h) {
      float scl = sbuf[h];
      float a0 = accE[h][0] * scl, a1 = accE[h][1] * scl;
      float4 pA = *(const float4*)&pbuf[h][0];
      float4 pB = *(const float4*)&pbuf[h][4];
      a0 += pA.x * kvp[0].x + pA.y * kvp[1].x + pA.z * kvp[2].x + pA.w * kvp[3].x
          + pB.x * kvp[4].x + pB.y * kvp[5].x + pB.z * kvp[6].x + pB.w * kvp[7].x;
      a1 += pA.x * kvp[0].y + pA.y * kvp[1].y + pA.z * kvp[2].y + pA.w * kvp[3].y
          + pB.x * kvp[4].y + pB.y * kvp[5].y + pB.z * kvp[6].y + pB.w * kvp[7].y;
      accE[h][0] = a0; accE[h][1] = a1;
    }
    __syncthreads();                   // B3: vmcnt(0) drain -> tile t+1 ready
  }

  // ---- epilogue: unnormalized acc (bf16) + (m,l)
  {
    long base = ((long)half * B_ + b) * H_;
#pragma unroll
    for (int h = 0; h < 16; ++h) {
      long idx = (base + h) * D_ + w * 128 + lane * 2;
      unsigned u0 = (unsigned short)f2bf(accE[h][0]);
      unsigned u1 = (unsigned short)f2bf(accE[h][1]);
      *(unsigned*)(part + idx) = u0 | (u1 << 16);
    }
    if (lane == 0) {
      ml[(base + w) * 2 + 0] = m_run;
      ml[(base + w) * 2 + 1] = l_run;
    }
  }
}

// ---------------------------------------------------------------------------
__global__ __launch_bounds__(256) void gate_final_k(
    const float* __restrict__ part, const float* __restrict__ bg,
    const float* __restrict__ x, const float* __restrict__ out1,
    float* __restrict__ y)
{
  const long i = (long)blockIdx.x * 256 + threadIdx.x;
  float z = bg[i & (D_ - 1)];
#pragma unroll
  for (int k = 0; k < 8; ++k) z += part[(long)k * (B_ * D_) + i];
  const float g = 1.0f / (1.0f + expf(-z));
  y[i] = x[i] + g * out1[i];
}

// ---------------------------------------------------------------------------
extern "C" void kernel_launch(void* const* d_in, const int* in_sizes, int n_in,
                              void* d_out, int out_size, void* d_ws, size_t ws_size,
                              hipStream_t stream)
{
  const float* x      = (const float*)d_in[0];
  const float* buffer = (const float*)d_in[1];
  const float* Wq     = (const float*)d_in[2];
  const float* Wk     = (const float*)d_in[3];
  const float* Wv     = (const float*)d_in[4];
  const float* Wo     = (const float*)d_in[5];
  const float* Wg     = (const float*)d_in[6];
  const float* bg     = (const float*)d_in[7];
  float* y = (float*)d_out;

  // workspace layout (float units)
  float* ws    = (float*)d_ws;
  float* q     = ws;                        // 262144
  float* qt    = ws + 262144;               // 4194304
  unsigned short* part_a = (unsigned short*)(ws + 4456448); // 8388608 bf16
  float* ml    = ws + 8650752;              // 8192
  float* o0    = ws + 8658944;              // 262144
  float* o1    = ws + 8921088;              // 262144
  float* partg = ws + 9183232;              // 8 * 262144 = 2097152
  unsigned short* wkT = (unsigned short*)(ws + 11280384);   // 16*2048*128 bf16

  const long S = (long)B_ * D_;

  // 0) WkT[h][e][d] bf16
  transpose_wk<<<dim3(32, 2, 16), 256, 0, stream>>>(Wk, wkT);

  // 1) q = x @ Wq.T   (K=2048, ksplit 8)
  gemm_mfma<false, 0><<<dim3(32, 1, 8), 256, 0, stream>>>(
      x, D_, 0, nullptr, 1 << 30, Wq, D_, 0, partg, D_, 0, S, 256);
  reduce_add_k<<<512, 256, 0, stream>>>(partg, 8, S, S, q);

  // 2) qt[b,h,e] = sum_d q[b,h*128+d] * WkT[h][e][d]   (K=128, per-head)
  gemm_mfma<true, 0><<<dim3(32, 16, 1), 256, 0, stream>>>(
      q, D_, DH_, nullptr, 1 << 30, wkT, DH_, (long)D_ * DH_,
      qt, H_ * D_, D_, 0, DH_);

  // 3) fused flash attention (combine folded into step 4's A-staging)
  fused_attn<<<dim3(B_, 2), 1024, 0, stream>>>(x, buffer, qt, part_a, ml);

  // 4) o0[b,h*128+d] = sum_e combine(part_a,ml)[b,h,e] * Wv[h*128+d,e]
  gemm_mfma<false, 1><<<dim3(2, 16, 8), 256, 0, stream>>>(
      (const float*)part_a, 0, 0, ml, 0, Wv, D_, (long)DH_ * D_,
      partg, D_, DH_, S, 256);
  reduce_add_k<<<512, 256, 0, stream>>>(partg, 8, S, S, o0);

  // 5) o1 = o0 @ Wo.T
  gemm_mfma<false, 0><<<dim3(32, 1, 8), 256, 0, stream>>>(
      o0, D_, 0, nullptr, 1 << 30, Wo, D_, 0, partg, D_, 0, S, 256);
  reduce_add_k<<<512, 256, 0, stream>>>(partg, 8, S, S, o1);

  // 6) gate: z = concat(x,o1) @ Wg.T + bg   (K=4096, A-switch at 2048)
  gemm_mfma<false, 0><<<dim3(32, 1, 8), 256, 0, stream>>>(
      x, D_, 0, o1, D_, Wg, 2 * D_, 0, partg, D_, 0, S, 512);
  gate_final_k<<<1024, 256, 0, stream>>>(partg, bg, x, o1, y);

  (void)in_sizes; (void)n_in; (void)out_size; (void)ws_size;
}